// Round 1
// baseline (40.761 us; speedup 1.0000x reference)
//
#include <hip/hip_runtime.h>

// FFM: out[b] = x_b . w_lin + b_lin + sum_{i<j} x_i W_ij x_j
// W_ij = dot(v[i, f_j, :], v[j, f_i, :])  (symmetric)
// Strategy: M = 0.5*(Wu + Wu^T) (zero diag) precomputed in bf16, packed in
// MFMA B-fragment order; then out = x . (M x + w) + b via 16x16x32 bf16 MFMA.

#define NFEAT 256
#define FK 256   // F*K = 32*8

typedef __attribute__((ext_vector_type(8))) short bf16x8;
typedef __attribute__((ext_vector_type(4))) float f32x4v;

__device__ __forceinline__ unsigned short f2bf(float x) {
    unsigned int u = __builtin_bit_cast(unsigned int, x);
    unsigned int r = u + 0x7FFFu + ((u >> 16) & 1u);
    return (unsigned short)(r >> 16);
}

// ---------------- Kernel 1: build packed M (bf16, B-fragment order) --------
// Fragment order for mfma_f32_16x16x32_bf16 B operand, assumed k-layout
// k = s*32 + (l>>4)*8 + i (any bijection is fine if A uses the same one).
// mpack element ((s*16 + ct)*64 + l)*8 + i  =  M[k][c],
//   k = s*32 + ((l>>4)&3)*8 + i,  c = ct*16 + (l&15)
__global__ __launch_bounds__(256) void k_build_m(
    const float* __restrict__ v, const int* __restrict__ fidx,
    uint4* __restrict__ mpack)
{
    int t = blockIdx.x * 256 + threadIdx.x;   // 8192 threads total
    int l  = t & 63;
    int ct = (t >> 6) & 15;
    int s  = t >> 10;                          // 0..7
    int c  = ct * 16 + (l & 15);
    int k0 = s * 32 + ((l >> 4) & 3) * 8;
    int fc = fidx[c];
    unsigned short h[8];
#pragma unroll
    for (int i = 0; i < 8; ++i) {
        int k = k0 + i;
        float acc = 0.f;
        if (k != c) {
            int fk = fidx[k];
            const float* va = v + k * FK + fc * 8;   // v[k, f_c, :]
            const float* vb = v + c * FK + fk * 8;   // v[c, f_k, :]
#pragma unroll
            for (int j = 0; j < 8; ++j) acc += va[j] * vb[j];
            acc *= 0.5f;
        }
        h[i] = f2bf(acc);
    }
    uint4 o;
    o.x = (unsigned int)h[0] | ((unsigned int)h[1] << 16);
    o.y = (unsigned int)h[2] | ((unsigned int)h[3] << 16);
    o.z = (unsigned int)h[4] | ((unsigned int)h[5] << 16);
    o.w = (unsigned int)h[6] | ((unsigned int)h[7] << 16);
    mpack[t] = o;
}

// ---------------- Kernel 2: main --------------------------------------------
// 512 blocks x 256 threads; 128 rows/block, 32 rows/wave.
// LDS: x tile as bf16, 16B chunks XOR-swizzled by (row&7) (T2 / G4).
__global__ __launch_bounds__(256, 2) void k_main(
    const float* __restrict__ x, const float* __restrict__ w_lin,
    const float* __restrict__ b_lin, const unsigned short* __restrict__ mpack,
    float* __restrict__ out)
{
    __shared__ unsigned short xs[128 * 256];  // 64 KB
    __shared__ float wsh[256];

    const int tid = threadIdx.x;
    const long rowbase = (long)blockIdx.x * 128;

    wsh[tid] = w_lin[tid];

    // ---- stage x: 128 rows x 256 cols f32 -> bf16 swizzled LDS ----
    const float* xg = x + rowbase * 256;
#pragma unroll 8
    for (int it = 0; it < 32; ++it) {
        int f   = it * 1024 + tid * 4;         // flat f32 index in tile
        float4 val = *(const float4*)(xg + f);
        int row = f >> 8;
        int col = f & 255;
        unsigned int lo = (unsigned int)f2bf(val.x) | ((unsigned int)f2bf(val.y) << 16);
        unsigned int hi = (unsigned int)f2bf(val.z) | ((unsigned int)f2bf(val.w) << 16);
        int chunk = col >> 3;                  // 16B chunk within row
        int byteoff = (row << 9) + ((chunk ^ (row & 7)) << 4) + ((col & 4) << 1);
        *(uint2*)((char*)xs + byteoff) = make_uint2(lo, hi);
    }
    __syncthreads();

    const int wv  = tid >> 6;       // wave 0..3 -> rows wv*32..wv*32+31
    const int l   = tid & 63;
    const int l15 = l & 15;
    const int lg  = (l >> 4) & 3;

    f32x4v acc[2][16];
#pragma unroll
    for (int rt = 0; rt < 2; ++rt)
#pragma unroll
        for (int ct = 0; ct < 16; ++ct) {
            f32x4v z = {0.f, 0.f, 0.f, 0.f};
            acc[rt][ct] = z;
        }

    const char* xsb = (const char*)xs;

    // ---- GEMM: t = X_tile(32x256) @ M(256x256), K-steps of 32 ----
#pragma unroll
    for (int s = 0; s < 8; ++s) {
        bf16x8 af[2];
#pragma unroll
        for (int rt = 0; rt < 2; ++rt) {
            int row   = wv * 32 + rt * 16 + l15;          // A row = lane&15
            int chunk = s * 4 + lg;                        // k = s*32+lg*8..+7
            int off   = (row << 9) + ((chunk ^ (row & 7)) << 4);
            af[rt] = *(const bf16x8*)(xsb + off);
        }
#pragma unroll
        for (int ct = 0; ct < 16; ++ct) {
            bf16x8 bfr = *(const bf16x8*)(mpack + (((s * 16 + ct) * 64 + l) << 3));
            acc[0][ct] = __builtin_amdgcn_mfma_f32_16x16x32_bf16(af[0], bfr, acc[0][ct], 0, 0, 0);
            acc[1][ct] = __builtin_amdgcn_mfma_f32_16x16x32_bf16(af[1], bfr, acc[1][ct], 0, 0, 0);
        }
    }

    // ---- dot phase: y[row] = sum_col x[row][col]*(t + w[col]) + b ----
    // C/D layout (m89-verified): col = lane&15, row = (lane>>4)*4 + reg
    float bv = b_lin[0];
#pragma unroll
    for (int rt = 0; rt < 2; ++rt) {
#pragma unroll
        for (int r = 0; r < 4; ++r) {
            int row = wv * 32 + rt * 16 + lg * 4 + r;
            int rsw = row & 7;
            float p = 0.f;
#pragma unroll
            for (int ct = 0; ct < 16; ++ct) {
                int col   = ct * 16 + l15;
                int chunk = col >> 3;
                int off   = (row << 9) + ((chunk ^ rsw) << 4) + ((col & 7) << 1);
                unsigned short hv = *(const unsigned short*)(xsb + off);
                float xv = __builtin_bit_cast(float, (unsigned int)hv << 16);
                p += xv * (acc[rt][ct][r] + wsh[col]);
            }
            p += __shfl_xor(p, 1);
            p += __shfl_xor(p, 2);
            p += __shfl_xor(p, 4);
            p += __shfl_xor(p, 8);
            if (l15 == 0) out[rowbase + row] = p + bv;
        }
    }
}

extern "C" void kernel_launch(void* const* d_in, const int* in_sizes, int n_in,
                              void* d_out, int out_size, void* d_ws, size_t ws_size,
                              hipStream_t stream) {
    const float* x     = (const float*)d_in[0];
    const float* w_lin = (const float*)d_in[1];
    const float* b_lin = (const float*)d_in[2];
    const float* v     = (const float*)d_in[3];
    const int*   fidx  = (const int*)d_in[4];
    float* out = (float*)d_out;
    unsigned short* mpack = (unsigned short*)d_ws;   // 128 KB

    k_build_m<<<32, 256, 0, stream>>>(v, fidx, (uint4*)mpack);
    k_main<<<512, 256, 0, stream>>>(x, w_lin, b_lin, mpack, out);
}

// Round 2
// 36.279 us; speedup vs baseline: 1.1235x; 1.1235x over previous
//
#include <hip/hip_runtime.h>

// FFM: out[b] = x_b . w_lin + b_lin + sum_{i<j} x_i W_ij x_j
// W_ij = dot(v[i, f_j, :], v[j, f_i, :])  (symmetric)
// M = 0.5*(Wu + Wu^T), zero diag, bf16, packed in MFMA B-fragment order.
// out = x . (M x + w) + b via 16x16x32 bf16 MFMA.
// R1: waves split output COLUMNS (not rows) -> M read once per block (4x less
// L2 traffic); cross-wave partial reduction in LDS.

#define FK 256   // F*K = 32*8

typedef __attribute__((ext_vector_type(8))) short bf16x8;
typedef __attribute__((ext_vector_type(4))) float f32x4v;

__device__ __forceinline__ unsigned short f2bf(float x) {
    unsigned int u = __builtin_bit_cast(unsigned int, x);
    unsigned int r = u + 0x7FFFu + ((u >> 16) & 1u);
    return (unsigned short)(r >> 16);
}

// ---------------- Kernel 1: build packed M (bf16, B-fragment order) --------
// mpack element ((s*16 + ct)*64 + l)*8 + i  =  M[k][c],
//   k = s*32 + ((l>>4)&3)*8 + i,  c = ct*16 + (l&15)
// (A-fragment loads use the same k-bijection, so MFMA dot is invariant.)
__global__ __launch_bounds__(128) void k_build_m(
    const float* __restrict__ v, const int* __restrict__ fidx,
    uint4* __restrict__ mpack)
{
    int t = blockIdx.x * 128 + threadIdx.x;   // 8192 threads total
    int l  = t & 63;
    int ct = (t >> 6) & 15;
    int s  = t >> 10;                          // 0..7
    int c  = ct * 16 + (l & 15);
    int k0 = s * 32 + ((l >> 4) & 3) * 8;
    int fc = fidx[c];
    unsigned short h[8];
#pragma unroll
    for (int i = 0; i < 8; ++i) {
        int k = k0 + i;
        float acc = 0.f;
        if (k != c) {
            int fk = fidx[k];
            const float* va = v + k * FK + fc * 8;   // v[k, f_c, :]
            const float* vb = v + c * FK + fk * 8;   // v[c, f_k, :]
#pragma unroll
            for (int j = 0; j < 8; ++j) acc += va[j] * vb[j];
            acc *= 0.5f;
        }
        h[i] = f2bf(acc);
    }
    uint4 o;
    o.x = (unsigned int)h[0] | ((unsigned int)h[1] << 16);
    o.y = (unsigned int)h[2] | ((unsigned int)h[3] << 16);
    o.z = (unsigned int)h[4] | ((unsigned int)h[5] << 16);
    o.w = (unsigned int)h[6] | ((unsigned int)h[7] << 16);
    mpack[t] = o;
}

// ---------------- Kernel 2: main --------------------------------------------
// 512 blocks x 256 threads; 128 rows/block; wave w owns cols [w*64, w*64+64).
__global__ __launch_bounds__(256, 2) void k_main(
    const float* __restrict__ x, const float* __restrict__ w_lin,
    const float* __restrict__ b_lin, const unsigned short* __restrict__ mpack,
    float* __restrict__ out)
{
    __shared__ unsigned short xs[128 * 256];  // 64 KB, XOR-swizzled 16B chunks
    __shared__ float wsh[256];
    __shared__ float part[128][4];

    const int tid = threadIdx.x;
    const long rowbase = (long)blockIdx.x * 128;

    wsh[tid] = w_lin[tid];

    // ---- stage x: 128 rows x 256 cols f32 -> bf16 swizzled LDS ----
    const float* xg = x + rowbase * 256;
#pragma unroll 8
    for (int it = 0; it < 32; ++it) {
        int f   = it * 1024 + tid * 4;         // flat f32 index in tile
        float4 val = *(const float4*)(xg + f);
        int row = f >> 8;
        int col = f & 255;
        unsigned int lo = (unsigned int)f2bf(val.x) | ((unsigned int)f2bf(val.y) << 16);
        unsigned int hi = (unsigned int)f2bf(val.z) | ((unsigned int)f2bf(val.w) << 16);
        int chunk = col >> 3;                  // 16B chunk within row
        int byteoff = (row << 9) + ((chunk ^ (row & 7)) << 4) + ((col & 4) << 1);
        *(uint2*)((char*)xs + byteoff) = make_uint2(lo, hi);
    }
    __syncthreads();

    const int wv  = tid >> 6;       // wave 0..3 -> col slice wv*64..+63
    const int l   = tid & 63;
    const int l15 = l & 15;
    const int lg  = (l >> 4) & 3;

    f32x4v acc[8][4];               // [row-tile rt][col-tile ctl within slice]
#pragma unroll
    for (int rt = 0; rt < 8; ++rt)
#pragma unroll
        for (int ctl = 0; ctl < 4; ++ctl) {
            f32x4v z = {0.f, 0.f, 0.f, 0.f};
            acc[rt][ctl] = z;
        }

    const char* xsb = (const char*)xs;

    // ---- GEMM: T = X_tile(128x256) @ M(:, slice), K-steps of 32 ----
#pragma unroll 2
    for (int s = 0; s < 8; ++s) {
        bf16x8 bfr[4];
#pragma unroll
        for (int ctl = 0; ctl < 4; ++ctl) {
            int ct = wv * 4 + ctl;
            bfr[ctl] = *(const bf16x8*)(mpack + (((s * 16 + ct) * 64 + l) << 3));
        }
#pragma unroll
        for (int rt = 0; rt < 8; ++rt) {
            int row   = rt * 16 + l15;          // A row = lane&15
            int chunk = s * 4 + lg;             // k = s*32+lg*8..+7
            int off   = (row << 9) + ((chunk ^ (row & 7)) << 4);
            bf16x8 af = *(const bf16x8*)(xsb + off);
#pragma unroll
            for (int ctl = 0; ctl < 4; ++ctl)
                acc[rt][ctl] = __builtin_amdgcn_mfma_f32_16x16x32_bf16(af, bfr[ctl], acc[rt][ctl], 0, 0, 0);
        }
    }

    // ---- dot phase: part[row][wv] = sum_{col in slice} x[row][col]*(t + w[col]) ----
    // C/D layout (m89-verified): col = lane&15, row = (lane>>4)*4 + reg
#pragma unroll
    for (int rt = 0; rt < 8; ++rt) {
#pragma unroll
        for (int r = 0; r < 4; ++r) {
            int row = rt * 16 + lg * 4 + r;
            int rsw = row & 7;
            float p = 0.f;
#pragma unroll
            for (int ctl = 0; ctl < 4; ++ctl) {
                int col   = wv * 64 + ctl * 16 + l15;
                int chunk = col >> 3;
                int off   = (row << 9) + ((chunk ^ rsw) << 4) + ((col & 7) << 1);
                unsigned short hv = *(const unsigned short*)(xsb + off);
                float xv = __builtin_bit_cast(float, (unsigned int)hv << 16);
                p += xv * (acc[rt][ctl][r] + wsh[col]);
            }
            p += __shfl_xor(p, 1);
            p += __shfl_xor(p, 2);
            p += __shfl_xor(p, 4);
            p += __shfl_xor(p, 8);
            if (l15 == 0) part[row][wv] = p;
        }
    }
    __syncthreads();

    // ---- final cross-wave reduction ----
    if (tid < 128) {
        float y = part[tid][0] + part[tid][1] + part[tid][2] + part[tid][3];
        out[rowbase + tid] = y + b_lin[0];
    }
}

extern "C" void kernel_launch(void* const* d_in, const int* in_sizes, int n_in,
                              void* d_out, int out_size, void* d_ws, size_t ws_size,
                              hipStream_t stream) {
    const float* x     = (const float*)d_in[0];
    const float* w_lin = (const float*)d_in[1];
    const float* b_lin = (const float*)d_in[2];
    const float* v     = (const float*)d_in[3];
    const int*   fidx  = (const int*)d_in[4];
    float* out = (float*)d_out;
    unsigned short* mpack = (unsigned short*)d_ws;   // 128 KB

    k_build_m<<<64, 128, 0, stream>>>(v, fidx, (uint4*)mpack);
    k_main<<<512, 256, 0, stream>>>(x, w_lin, b_lin, mpack, out);
}

// Round 3
// 29.472 us; speedup vs baseline: 1.3830x; 1.2310x over previous
//
#include <hip/hip_runtime.h>
#include <hip/hip_bf16.h>

// FFM: out[b] = x_b . w_lin + b_lin + sum_{i<j} x_i W_ij x_j
// W_ij = dot(v[i, f_j, :], v[j, f_i, :])  (symmetric)
// M = 0.5*(Wu + Wu^T), zero diag, bf16, packed in MFMA B-fragment order.
// out = x . (M x + w) + b via 16x16x32 bf16 MFMA.
// R2: subtiled LDS [row/4][col/16][row&3][col&15] (conflict-free, no XOR),
//     64 rows/block @ 4 blocks/CU, DPP row_ror reduction, w folded into acc.

#define FK 256   // F*K = 32*8

typedef __attribute__((ext_vector_type(8))) short bf16x8;
typedef __attribute__((ext_vector_type(4))) float f32x4v;

__device__ __forceinline__ unsigned short f2bf(float x) {
    return __builtin_bit_cast(unsigned short, __float2bfloat16(x));
}

template<int CTRL>
__device__ __forceinline__ float dppadd(float v) {
    int t = __builtin_amdgcn_update_dpp(0, __builtin_bit_cast(int, v),
                                        CTRL, 0xf, 0xf, true);
    return v + __builtin_bit_cast(float, t);
}

// ---------------- Kernel 1: build packed M (bf16, B-fragment order) --------
// mpack element ((s*16 + ct)*64 + l)*8 + i  =  M[k][c],
//   k = s*32 + ((l>>4)&3)*8 + i,  c = ct*16 + (l&15)
__global__ __launch_bounds__(128) void k_build_m(
    const float* __restrict__ v, const int* __restrict__ fidx,
    uint4* __restrict__ mpack)
{
    int t = blockIdx.x * 128 + threadIdx.x;   // 8192 threads total
    int l  = t & 63;
    int ct = (t >> 6) & 15;
    int s  = t >> 10;                          // 0..7
    int c  = ct * 16 + (l & 15);
    int k0 = s * 32 + ((l >> 4) & 3) * 8;
    int fc = fidx[c];
    unsigned short h[8];
#pragma unroll
    for (int i = 0; i < 8; ++i) {
        int k = k0 + i;
        float acc = 0.f;
        if (k != c) {
            int fk = fidx[k];
            const float* va = v + k * FK + fc * 8;   // v[k, f_c, :]
            const float* vb = v + c * FK + fk * 8;   // v[c, f_k, :]
#pragma unroll
            for (int j = 0; j < 8; ++j) acc += va[j] * vb[j];
            acc *= 0.5f;
        }
        h[i] = f2bf(acc);
    }
    uint4 o;
    o.x = (unsigned int)h[0] | ((unsigned int)h[1] << 16);
    o.y = (unsigned int)h[2] | ((unsigned int)h[3] << 16);
    o.z = (unsigned int)h[4] | ((unsigned int)h[5] << 16);
    o.w = (unsigned int)h[6] | ((unsigned int)h[7] << 16);
    mpack[t] = o;
}

// ---------------- Kernel 2: main --------------------------------------------
// 1024 blocks x 256 threads; 64 rows/block; wave w owns cols [w*64, w*64+64).
// xs element (row,col) at flat index ((row>>2)*16 + (col>>4))*64
//                                    + (row&3)*16 + (col&15)
__global__ __launch_bounds__(256, 4) void k_main(
    const float* __restrict__ x, const float* __restrict__ w_lin,
    const float* __restrict__ b_lin, const unsigned short* __restrict__ mpack,
    float* __restrict__ out)
{
    __shared__ unsigned short xs[64 * 256];   // 32 KB, subtiled
    __shared__ float wsh[256];
    __shared__ float part[4][64];

    const int tid = threadIdx.x;
    const int wv  = tid >> 6;        // wave 0..3 -> col slice wv*64..+63
    const int l   = tid & 63;
    const int l15 = l & 15;
    const int lg  = l >> 4;          // 0..3
    const long rowbase = (long)blockIdx.x * 64;

    wsh[tid] = w_lin[tid];

    // ---- stage: per wave-iter, 4 rows (one per 16-lane group) x 64 cols ----
    const float* xg = x + rowbase * 256;
    char* xsb = (char*)xs;
#pragma unroll
    for (int it = 0; it < 16; ++it) {
        int row  = it * 4 + lg;
        int colb = wv * 64 + l15 * 4;
        float4 val = *(const float4*)(xg + row * 256 + colb);
        unsigned long h0 = f2bf(val.x), h1 = f2bf(val.y),
                      h2 = f2bf(val.z), h3 = f2bf(val.w);
        unsigned long pk = h0 | (h1 << 16) | (h2 << 32) | (h3 << 48);
        int byteoff = (it * 16 + wv * 4 + (l15 >> 2)) * 128
                    + lg * 32 + (l15 & 3) * 8;
        *(unsigned long*)(xsb + byteoff) = pk;
    }
    __syncthreads();

    // ---- w slice into regs; fold into accumulator init ----
    float wv4[4];
#pragma unroll
    for (int ctl = 0; ctl < 4; ++ctl)
        wv4[ctl] = wsh[wv * 64 + ctl * 16 + l15];

    f32x4v acc[4][4];                // [row-tile][col-tile in slice]
#pragma unroll
    for (int rt = 0; rt < 4; ++rt)
#pragma unroll
        for (int ctl = 0; ctl < 4; ++ctl) {
            f32x4v z = {wv4[ctl], wv4[ctl], wv4[ctl], wv4[ctl]};
            acc[rt][ctl] = z;
        }

    // ---- GEMM: acc = w + X_tile(64x256) @ M(:, slice) ----
#pragma unroll
    for (int s = 0; s < 8; ++s) {
        bf16x8 bfr[4];
#pragma unroll
        for (int ctl = 0; ctl < 4; ++ctl) {
            int ct = wv * 4 + ctl;
            bfr[ctl] = *(const bf16x8*)(mpack + (((s * 16 + ct) * 64 + l) << 3));
        }
#pragma unroll
        for (int rt = 0; rt < 4; ++rt) {
            int off = ((rt * 4 + (l15 >> 2)) * 16 + s * 2 + (lg >> 1)) * 128
                    + (l15 & 3) * 32 + (lg & 1) * 16;
            bf16x8 af = *(const bf16x8*)(xsb + off);
#pragma unroll
            for (int ctl = 0; ctl < 4; ++ctl)
                acc[rt][ctl] = __builtin_amdgcn_mfma_f32_16x16x32_bf16(
                    af, bfr[ctl], acc[rt][ctl], 0, 0, 0);
        }
    }

    // ---- dot phase: p[r] = sum_cols x[row][col] * acc ----
    // C/D layout (m89): col = ct*16 + (lane&15), row = rt*16 + (lane>>4)*4 + r
#pragma unroll
    for (int rt = 0; rt < 4; ++rt) {
        float p0 = 0.f, p1 = 0.f, p2 = 0.f, p3 = 0.f;
#pragma unroll
        for (int ctl = 0; ctl < 4; ++ctl) {
            int base = ((rt * 4 + lg) * 16 + wv * 4 + ctl) * 128 + l15 * 2;
            unsigned short h0 = *(const unsigned short*)(xsb + base);
            unsigned short h1 = *(const unsigned short*)(xsb + base + 32);
            unsigned short h2 = *(const unsigned short*)(xsb + base + 64);
            unsigned short h3 = *(const unsigned short*)(xsb + base + 96);
            p0 += __builtin_bit_cast(float, (unsigned int)h0 << 16) * acc[rt][ctl][0];
            p1 += __builtin_bit_cast(float, (unsigned int)h1 << 16) * acc[rt][ctl][1];
            p2 += __builtin_bit_cast(float, (unsigned int)h2 << 16) * acc[rt][ctl][2];
            p3 += __builtin_bit_cast(float, (unsigned int)h3 << 16) * acc[rt][ctl][3];
        }
        // reduce over the 16-lane group via DPP row rotations (no DS ops)
        p0 = dppadd<0x121>(p0); p0 = dppadd<0x122>(p0); p0 = dppadd<0x124>(p0); p0 = dppadd<0x128>(p0);
        p1 = dppadd<0x121>(p1); p1 = dppadd<0x122>(p1); p1 = dppadd<0x124>(p1); p1 = dppadd<0x128>(p1);
        p2 = dppadd<0x121>(p2); p2 = dppadd<0x122>(p2); p2 = dppadd<0x124>(p2); p2 = dppadd<0x128>(p2);
        p3 = dppadd<0x121>(p3); p3 = dppadd<0x122>(p3); p3 = dppadd<0x124>(p3); p3 = dppadd<0x128>(p3);
        if (l15 == 0) {
            float4 pv = make_float4(p0, p1, p2, p3);
            *(float4*)&part[wv][rt * 16 + lg * 4] = pv;
        }
    }
    __syncthreads();

    // ---- final cross-wave reduction ----
    if (tid < 64) {
        float y = part[0][tid] + part[1][tid] + part[2][tid] + part[3][tid];
        out[rowbase + tid] = y + b_lin[0];
    }
}

extern "C" void kernel_launch(void* const* d_in, const int* in_sizes, int n_in,
                              void* d_out, int out_size, void* d_ws, size_t ws_size,
                              hipStream_t stream) {
    const float* x     = (const float*)d_in[0];
    const float* w_lin = (const float*)d_in[1];
    const float* b_lin = (const float*)d_in[2];
    const float* v     = (const float*)d_in[3];
    const int*   fidx  = (const int*)d_in[4];
    float* out = (float*)d_out;
    unsigned short* mpack = (unsigned short*)d_ws;   // 128 KB

    k_build_m<<<64, 128, 0, stream>>>(v, fidx, (uint4*)mpack);
    k_main<<<1024, 256, 0, stream>>>(x, w_lin, b_lin, mpack, out);
}

// Round 4
// 27.522 us; speedup vs baseline: 1.4810x; 1.0709x over previous
//
#include <hip/hip_runtime.h>
#include <hip/hip_bf16.h>

// FFM: out[b] = x_b . w_lin + b_lin + sum_{i<j} x_i W_ij x_j
// W_ij = dot(v[i, f_j, :], v[j, f_i, :])  (symmetric)
// M = 0.5*(Wu + Wu^T), zero diag, bf16, packed in MFMA B-fragment order.
// out = x . (M x + w) + b via 16x16x32 bf16 MFMA.
// R3: double-buffered 2-tiles/block pipeline (prefetch tile1 into regs while
//     computing tile0); k_build_m at 2x parallelism (uint2/thread).

#define FK 256   // F*K = 32*8

typedef __attribute__((ext_vector_type(8))) short bf16x8;
typedef __attribute__((ext_vector_type(4))) float f32x4v;

__device__ __forceinline__ unsigned short f2bf(float x) {
    return __builtin_bit_cast(unsigned short, __float2bfloat16(x));
}

template<int CTRL>
__device__ __forceinline__ float dppadd(float v) {
    int t = __builtin_amdgcn_update_dpp(0, __builtin_bit_cast(int, v),
                                        CTRL, 0xf, 0xf, true);
    return v + __builtin_bit_cast(float, t);
}

// ---------------- Kernel 1: build packed M (bf16, B-fragment order) --------
// mpack uint4 element ((s*16 + ct)*64 + l), lane-elem i = M[k][c],
//   k = s*32 + ((l>>4)&3)*8 + i,  c = ct*16 + (l&15)
// Here one thread produces a uint2 (4 elems, h = which half).
__global__ __launch_bounds__(64) void k_build_m(
    const float* __restrict__ v, const int* __restrict__ fidx,
    uint2* __restrict__ mpack2)
{
    int t = blockIdx.x * 64 + threadIdx.x;    // 16384 threads
    int h  = t & 1;
    int l  = (t >> 1) & 63;
    int ct = (t >> 7) & 15;
    int s  = t >> 11;                          // 0..7
    int c  = ct * 16 + (l & 15);
    int k0 = s * 32 + ((l >> 4) & 3) * 8 + h * 4;
    int fc = fidx[c];
    unsigned short hh[4];
#pragma unroll
    for (int i = 0; i < 4; ++i) {
        int k = k0 + i;
        float acc = 0.f;
        if (k != c) {
            int fk = fidx[k];
            const float* va = v + k * FK + fc * 8;   // v[k, f_c, :]
            const float* vb = v + c * FK + fk * 8;   // v[c, f_k, :]
#pragma unroll
            for (int j = 0; j < 8; ++j) acc += va[j] * vb[j];
            acc *= 0.5f;
        }
        hh[i] = f2bf(acc);
    }
    uint2 o;
    o.x = (unsigned int)hh[0] | ((unsigned int)hh[1] << 16);
    o.y = (unsigned int)hh[2] | ((unsigned int)hh[3] << 16);
    mpack2[t] = o;
}

// ---------------- Kernel 2: main --------------------------------------------
// 512 blocks x 256 threads; each block processes 2 consecutive 64-row tiles
// with double-buffered LDS. Wave w owns cols [w*64, w*64+64).
// xs element (row,col) at flat u16 index ((row>>2)*16 + (col>>4))*64
//                                        + (row&3)*16 + (col&15)

__device__ __forceinline__ void compute_tile(
    const unsigned short* xs, const unsigned short* __restrict__ mpack,
    const float* wv4, float bv, float* __restrict__ outp,
    int wv, int l, int l15, int lg, int tid, float (*part)[64])
{
    const char* xsb = (const char*)xs;

    f32x4v acc[4][4];                // [row-tile][col-tile in slice]
#pragma unroll
    for (int rt = 0; rt < 4; ++rt)
#pragma unroll
        for (int ctl = 0; ctl < 4; ++ctl) {
            f32x4v z = {wv4[ctl], wv4[ctl], wv4[ctl], wv4[ctl]};
            acc[rt][ctl] = z;
        }

    // ---- GEMM: acc = w + X_tile(64x256) @ M(:, slice) ----
#pragma unroll
    for (int s = 0; s < 8; ++s) {
        bf16x8 bfr[4];
#pragma unroll
        for (int ctl = 0; ctl < 4; ++ctl) {
            int ct = wv * 4 + ctl;
            bfr[ctl] = *(const bf16x8*)(mpack + (((s * 16 + ct) * 64 + l) << 3));
        }
#pragma unroll
        for (int rt = 0; rt < 4; ++rt) {
            int off = ((rt * 4 + (l15 >> 2)) * 16 + s * 2 + (lg >> 1)) * 128
                    + (l15 & 3) * 32 + (lg & 1) * 16;
            bf16x8 af = *(const bf16x8*)(xsb + off);
#pragma unroll
            for (int ctl = 0; ctl < 4; ++ctl)
                acc[rt][ctl] = __builtin_amdgcn_mfma_f32_16x16x32_bf16(
                    af, bfr[ctl], acc[rt][ctl], 0, 0, 0);
        }
    }

    // ---- dot phase: p[r] = sum_cols x[row][col] * acc ----
    // C/D layout (m89): col = ct*16 + (lane&15), row = rt*16 + (lane>>4)*4 + r
#pragma unroll
    for (int rt = 0; rt < 4; ++rt) {
        float p0 = 0.f, p1 = 0.f, p2 = 0.f, p3 = 0.f;
#pragma unroll
        for (int ctl = 0; ctl < 4; ++ctl) {
            int base = ((rt * 4 + lg) * 16 + wv * 4 + ctl) * 128 + l15 * 2;
            unsigned short h0 = *(const unsigned short*)(xsb + base);
            unsigned short h1 = *(const unsigned short*)(xsb + base + 32);
            unsigned short h2 = *(const unsigned short*)(xsb + base + 64);
            unsigned short h3 = *(const unsigned short*)(xsb + base + 96);
            p0 += __builtin_bit_cast(float, (unsigned int)h0 << 16) * acc[rt][ctl][0];
            p1 += __builtin_bit_cast(float, (unsigned int)h1 << 16) * acc[rt][ctl][1];
            p2 += __builtin_bit_cast(float, (unsigned int)h2 << 16) * acc[rt][ctl][2];
            p3 += __builtin_bit_cast(float, (unsigned int)h3 << 16) * acc[rt][ctl][3];
        }
        p0 = dppadd<0x121>(p0); p0 = dppadd<0x122>(p0); p0 = dppadd<0x124>(p0); p0 = dppadd<0x128>(p0);
        p1 = dppadd<0x121>(p1); p1 = dppadd<0x122>(p1); p1 = dppadd<0x124>(p1); p1 = dppadd<0x128>(p1);
        p2 = dppadd<0x121>(p2); p2 = dppadd<0x122>(p2); p2 = dppadd<0x124>(p2); p2 = dppadd<0x128>(p2);
        p3 = dppadd<0x121>(p3); p3 = dppadd<0x122>(p3); p3 = dppadd<0x124>(p3); p3 = dppadd<0x128>(p3);
        if (l15 == 0) {
            float4 pv = make_float4(p0, p1, p2, p3);
            *(float4*)&part[wv][rt * 16 + lg * 4] = pv;
        }
    }
    __syncthreads();
    if (tid < 64)
        outp[tid] = part[0][tid] + part[1][tid] + part[2][tid] + part[3][tid] + bv;
}

__global__ __launch_bounds__(256, 2) void k_main(
    const float* __restrict__ x, const float* __restrict__ w_lin,
    const float* __restrict__ b_lin, const unsigned short* __restrict__ mpack,
    float* __restrict__ out)
{
    __shared__ unsigned short xs[2][64 * 256];   // 2 x 32 KB, subtiled
    __shared__ float part[4][64];

    const int tid = threadIdx.x;
    const int wv  = tid >> 6;        // wave 0..3 -> col slice wv*64..+63
    const int l   = tid & 63;
    const int l15 = l & 15;
    const int lg  = l >> 4;          // 0..3
    const long tilebase = (long)blockIdx.x * 128;

    // w slice (L2-resident, 4 scalar loads) + b
    float wv4[4];
#pragma unroll
    for (int ctl = 0; ctl < 4; ++ctl)
        wv4[ctl] = w_lin[wv * 64 + ctl * 16 + l15];
    float bv = b_lin[0];

    const int colb = wv * 64 + l15 * 4;

    // ---- stage tile0 directly into buf0 ----
    {
        const float* xg = x + tilebase * 256;
        char* xsb = (char*)xs[0];
#pragma unroll
        for (int it = 0; it < 16; ++it) {
            int row = it * 4 + lg;
            float4 val = *(const float4*)(xg + row * 256 + colb);
            unsigned long h0 = f2bf(val.x), h1 = f2bf(val.y),
                          h2 = f2bf(val.z), h3 = f2bf(val.w);
            unsigned long pk = h0 | (h1 << 16) | (h2 << 32) | (h3 << 48);
            int byteoff = (it * 16 + wv * 4 + (l15 >> 2)) * 128
                        + lg * 32 + (l15 & 3) * 8;
            *(unsigned long*)(xsb + byteoff) = pk;
        }
    }
    __syncthreads();

    // ---- issue tile1 loads into regs (no wait) ----
    float4 pre[16];
    {
        const float* xg = x + (tilebase + 64) * 256;
#pragma unroll
        for (int it = 0; it < 16; ++it) {
            int row = it * 4 + lg;
            pre[it] = *(const float4*)(xg + row * 256 + colb);
        }
    }

    // ---- compute tile0 (overlaps tile1 HBM reads) ----
    compute_tile(xs[0], mpack, wv4, bv, out + tilebase, wv, l, l15, lg, tid, part);

    // ---- convert + write tile1 into buf1 ----
    {
        char* xsb = (char*)xs[1];
#pragma unroll
        for (int it = 0; it < 16; ++it) {
            unsigned long h0 = f2bf(pre[it].x), h1 = f2bf(pre[it].y),
                          h2 = f2bf(pre[it].z), h3 = f2bf(pre[it].w);
            unsigned long pk = h0 | (h1 << 16) | (h2 << 32) | (h3 << 48);
            int byteoff = (it * 16 + wv * 4 + (l15 >> 2)) * 128
                        + lg * 32 + (l15 & 3) * 8;
            *(unsigned long*)(xsb + byteoff) = pk;
        }
    }
    __syncthreads();

    // ---- compute tile1 ----
    compute_tile(xs[1], mpack, wv4, bv, out + tilebase + 64, wv, l, l15, lg, tid, part);
}

extern "C" void kernel_launch(void* const* d_in, const int* in_sizes, int n_in,
                              void* d_out, int out_size, void* d_ws, size_t ws_size,
                              hipStream_t stream) {
    const float* x     = (const float*)d_in[0];
    const float* w_lin = (const float*)d_in[1];
    const float* b_lin = (const float*)d_in[2];
    const float* v     = (const float*)d_in[3];
    const int*   fidx  = (const int*)d_in[4];
    float* out = (float*)d_out;
    unsigned short* mpack = (unsigned short*)d_ws;   // 128 KB

    k_build_m<<<256, 64, 0, stream>>>(v, fidx, (uint2*)mpack);
    k_main<<<512, 256, 0, stream>>>(x, w_lin, b_lin, mpack, out);
}